// Round 14
// baseline (558.385 us; speedup 1.0000x reference)
//
#include <hip/hip_runtime.h>
#include <math.h>
#include <stdint.h>

#define NUM_EMB 512
#define EMB_DIM 64
#define S_SPATIAL 32768   // 32*32*32
#define BATCH 4
#define NVEC (BATCH * S_SPATIAL)  // 131072 vectors
#define KTILE 8
#define NTILE (NUM_EMB / KTILE)   // 64 tiles of 8 codes

// Workspace layout (d_ws):
//   0   : double loss_accum
//   256 : float  cbnorm[512]

// ---------------------------------------------------------------------------
__global__ void vq_prep(const float* __restrict__ cb,
                        float* __restrict__ cbnorm,
                        double* __restrict__ loss_accum) {
    int k = blockIdx.x * blockDim.x + threadIdx.x;
    if (k == 0) *loss_accum = 0.0;
    if (k < NUM_EMB) {
        const float* e = cb + k * EMB_DIM;
        float s = 0.f;
        #pragma unroll
        for (int c = 0; c < EMB_DIM; ++c)
            s = __fadd_rn(s, __fmul_rn(e[c], e[c]));
        cbnorm[k] = s;
    }
}

// ---------------------------------------------------------------------------
// Block = 256 vectors, x tile in LDS [comp][vec] (64KB). R12 diagnosis:
// codebook s_loads (SMEM) + x ds_reads share lgkmcnt; SMEM returns
// OUT-OF-ORDER within lgkm, so every ds_read consume forces lgkmcnt(0),
// draining the whole codebook burst -> 30% VALU duty. Fix: force the
// codebook base address into a VGPR (asm "+v"), so codebook reads become
// global_load_dwordx4 on vmcnt (in-order, counted waits, pipelines across
// the FMA stream; uniform address -> one fetch broadcast, L2-resident).
// ds stream is now pure -> counted lgkmcnt waits. FMA order per
// accumulator unchanged (c ascending) -> bit-identical to R12 (absmax
// 7.629395e-06 proven on HW).
// ---------------------------------------------------------------------------
__global__ __launch_bounds__(256) void vq_main(
        const float* __restrict__ in,
        const float* __restrict__ cb,
        const float* __restrict__ cbnorm,
        float* __restrict__ outq,          // d_out + 1 (quantized, [B,C,D,H,W])
        double* __restrict__ loss_accum) {
    __shared__ float ldsx[EMB_DIM * 256];  // [comp][vec], 64 KB

    const int tid = threadIdx.x;
    const int n = blockIdx.x * 256 + tid;  // this thread's vector id
    const int b = n >> 15;                 // n / S_SPATIAL
    const int s0 = (blockIdx.x * 256) & (S_SPATIAL - 1);  // block's spatial base
    const size_t S = (size_t)S_SPATIAL;

    const float* xp = in + (size_t)b * EMB_DIM * S_SPATIAL + s0;

    // ---- VGPR-forced codebook pointers: loads go to vmcnt, not lgkmcnt ----
    uintptr_t cba = (uintptr_t)cb;
    asm volatile("" : "+v"(cba));
    const float* cbv = (const float*)cba;
    uintptr_t cbna = (uintptr_t)cbnorm;
    asm volatile("" : "+v"(cbna));
    const float* cbnv = (const float*)cbna;

    // ---- stage x tile into LDS; accumulate xn (sequential c order) ----
    float xn = 0.f;
    #pragma unroll
    for (int c = 0; c < EMB_DIM; ++c) {
        float v = xp[(size_t)c * S + tid];       // coalesced
        ldsx[c * 256 + tid] = v;                 // conflict-free write
        xn = __fadd_rn(xn, __fmul_rn(v, v));
    }
    __syncthreads();

    // ---- argmin over 512 codes, 64 tiles x 8 codes ----
    float best = INFINITY;
    int bestk = 0;
    for (int t = 0; t < NTILE; ++t) {
        const float4* Ev = (const float4*)(cbv + (size_t)t * KTILE * EMB_DIM);
        const float4* Cn = (const float4*)(cbnv + t * KTILE);

        float a[KTILE];
        #pragma unroll
        for (int j = 0; j < KTILE; ++j) a[j] = 0.f;

        // c in blocks of 4; per a[j] the comps still accumulate in ascending
        // c order -> chain identical to R12.
        #pragma unroll 4
        for (int c4 = 0; c4 < EMB_DIM / 4; ++c4) {
            float x0 = ldsx[(4*c4+0) * 256 + tid];
            float x1 = ldsx[(4*c4+1) * 256 + tid];
            float x2 = ldsx[(4*c4+2) * 256 + tid];
            float x3 = ldsx[(4*c4+3) * 256 + tid];
            #pragma unroll
            for (int j = 0; j < KTILE; ++j) {
                const float4 e = Ev[j * (EMB_DIM/4) + c4];  // uniform vmem
                a[j] = fmaf(x0, e.x, a[j]);
                a[j] = fmaf(x1, e.y, a[j]);
                a[j] = fmaf(x2, e.z, a[j]);
                a[j] = fmaf(x3, e.w, a[j]);
            }
        }

        const float4 cn0 = Cn[0];
        const float4 cn1 = Cn[1];
        float cbn_[KTILE] = {cn0.x, cn0.y, cn0.z, cn0.w,
                             cn1.x, cn1.y, cn1.z, cn1.w};
        #pragma unroll
        for (int j = 0; j < KTILE; ++j) {
            float d = __fsub_rn(__fadd_rn(xn, cbn_[j]),
                                __fmul_rn(2.f, a[j]));
            if (d < best) { best = d; bestk = t * KTILE + j; }
        }
    }

    // ---- gather winning code, write output, loss partial ----
    const float4* q = (const float4*)(cb + (size_t)bestk * EMB_DIM);
    float* op = outq + (size_t)b * EMB_DIM * S_SPATIAL + s0 + tid;
    float lsum = 0.f;
    #pragma unroll
    for (int i = 0; i < EMB_DIM / 4; ++i) {
        const float4 qv = q[i];                  // per-lane gather, L2-hot
        float x0 = ldsx[(4*i+0) * 256 + tid];
        float x1 = ldsx[(4*i+1) * 256 + tid];
        float x2 = ldsx[(4*i+2) * 256 + tid];
        float x3 = ldsx[(4*i+3) * 256 + tid];
        op[(size_t)(4*i+0) * S] = qv.x;
        op[(size_t)(4*i+1) * S] = qv.y;
        op[(size_t)(4*i+2) * S] = qv.z;
        op[(size_t)(4*i+3) * S] = qv.w;
        float d0 = __fsub_rn(qv.x, x0);
        float d1 = __fsub_rn(qv.y, x1);
        float d2 = __fsub_rn(qv.z, x2);
        float d3 = __fsub_rn(qv.w, x3);
        lsum = __fadd_rn(lsum, __fmul_rn(d0, d0));
        lsum = __fadd_rn(lsum, __fmul_rn(d1, d1));
        lsum = __fadd_rn(lsum, __fmul_rn(d2, d2));
        lsum = __fadd_rn(lsum, __fmul_rn(d3, d3));
    }

    // ---- block reduction of lsum -> one double atomicAdd per block ----
    double ls = (double)lsum;
    #pragma unroll
    for (int off = 32; off > 0; off >>= 1)
        ls += __shfl_down(ls, off, 64);
    __shared__ double wsum[4];
    const int lane = tid & 63;
    const int wid  = tid >> 6;
    if (lane == 0) wsum[wid] = ls;
    __syncthreads();
    if (tid == 0) {
        double tsum = ((wsum[0] + wsum[1]) + (wsum[2] + wsum[3]));
        atomicAdd(loss_accum, tsum);
    }
}

// ---------------------------------------------------------------------------
__global__ void vq_final(const double* __restrict__ loss_accum,
                         float* __restrict__ out0) {
    double m = *loss_accum / (double)((long long)NVEC * EMB_DIM);
    float mf = (float)m;
    out0[0] = __fadd_rn(mf, __fmul_rn(0.25f, mf));
}

extern "C" void kernel_launch(void* const* d_in, const int* in_sizes, int n_in,
                              void* d_out, int out_size, void* d_ws, size_t ws_size,
                              hipStream_t stream) {
    const float* in = (const float*)d_in[0];   // [4, 64, 32, 32, 32]
    const float* cb = (const float*)d_in[1];   // [512, 64]
    float* out = (float*)d_out;                // [0]=loss, [1..]=quantized

    double* loss_accum = (double*)d_ws;
    float* cbnorm = (float*)((char*)d_ws + 256);

    vq_prep<<<4, 128, 0, stream>>>(cb, cbnorm, loss_accum);
    vq_main<<<NVEC / 256, 256, 0, stream>>>(in, cb, cbnorm, out + 1, loss_accum);
    vq_final<<<1, 1, 0, stream>>>(loss_accum, out);
}